// Round 7
// baseline (1410.233 us; speedup 1.0000x reference)
//
#include <hip/hip_runtime.h>
#include <hip/hip_bf16.h>

// B=100000, C=64, R=128, H=32
// out[b,r,i,j] = sum_c w[b,r,c] * v[b,c,i]*v[b,c,j]
// w = relu(||v||_c @ W1 + b1) @ W2 + b2
//
// R7: "flood" structure. grid = (B/16 batch-groups) x (R/16 r-tiles) = 50000
// independent small blocks; each does ONE stage1->barrier->stage2->store pass.
// h precomputed by prep_h into ws. rt = bid&7 -> XCD-local w2t slice (64 KB).

typedef float f32x4 __attribute__((ext_vector_type(4)));
typedef __bf16 bf16x8 __attribute__((ext_vector_type(8)));
typedef unsigned int u32x4 __attribute__((ext_vector_type(4)));

static __device__ __forceinline__ unsigned short bf_bits(float f) {
  __hip_bfloat16 h = __float2bfloat16(f);
  return *reinterpret_cast<const unsigned short*>(&h);
}
static __device__ __forceinline__ unsigned int pack_bf2(float a, float b) {
  return (unsigned int)bf_bits(a) | ((unsigned int)bf_bits(b) << 16);
}

// ---- kernel 0: W2 [32][8192] fp32 -> W2T [8192][32] bf16 ----
__global__ void prep_w2t(const float* __restrict__ W2, unsigned short* __restrict__ w2t) {
  int rc = blockIdx.x * 256 + threadIdx.x;   // 0..8191
  unsigned int u[16];
#pragma unroll
  for (int kp = 0; kp < 16; ++kp) {
    float a = W2[(size_t)(2 * kp) * 8192 + rc];
    float b = W2[(size_t)(2 * kp + 1) * 8192 + rc];
    u[kp] = pack_bf2(a, b);
  }
  unsigned int* dst = reinterpret_cast<unsigned int*>(w2t + (size_t)rc * 32);
#pragma unroll
  for (int j = 0; j < 16; ++j) dst[j] = u[j];
}

// ---- kernel 1: h[b][k] = relu(norm(v[b])@W1 + b1), bf16 [100000][32] ----
__global__ void prep_h(const float* __restrict__ v, const float* __restrict__ W1,
                       const float* __restrict__ b1, unsigned short* __restrict__ hws) {
  __shared__ float v_lds[64 * 192];    // 48 KB
  __shared__ float s_lds[64 * 68];     // 17 KB
  __shared__ float W1T[32 * 68];       // 8.5 KB
  const int t = threadIdx.x;
  const int b0 = blockIdx.x * 64;
  const int rem = (100000 - b0 < 64) ? (100000 - b0) : 64;

#pragma unroll
  for (int j = 0; j < 8; ++j) {
    int p = t + j * 256;               // W1 [64][32]: c=p>>5, k=p&31
    W1T[(p & 31) * 68 + (p >> 5)] = W1[p];
  }
  {
    const f32x4* src = reinterpret_cast<const f32x4*>(v + (size_t)b0 * 192);
    f32x4* dst = reinterpret_cast<f32x4*>(v_lds);
    const int nq = rem * 48;
#pragma unroll
    for (int j = 0; j < 12; ++j) {
      int p = t + j * 256;
      if (p < nq) dst[p] = src[p];
    }
  }
  __syncthreads();

  const int b = t >> 2, kq = t & 3;    // b-local, k-quarter
#pragma unroll
  for (int cc = 0; cc < 16; ++cc) {
    int c = kq * 16 + cc;
    float vx = v_lds[b * 192 + c * 3];
    float vy = v_lds[b * 192 + c * 3 + 1];
    float vz = v_lds[b * 192 + c * 3 + 2];
    s_lds[b * 68 + c] = sqrtf(vx * vx + vy * vy + vz * vz);
  }
  __syncthreads();

  if (b < rem) {
    float acc[8];
#pragma unroll
    for (int e = 0; e < 8; ++e) acc[e] = b1[kq * 8 + e];
#pragma unroll
    for (int c4 = 0; c4 < 16; ++c4) {
      f32x4 sv = *reinterpret_cast<const f32x4*>(&s_lds[b * 68 + c4 * 4]);
#pragma unroll
      for (int e = 0; e < 8; ++e) {
        f32x4 wr = *reinterpret_cast<const f32x4*>(&W1T[(kq * 8 + e) * 68 + c4 * 4]);
#pragma unroll
        for (int u = 0; u < 4; ++u) acc[e] = fmaf(sv[u], wr[u], acc[e]);
      }
    }
    u32x4 pk;
#pragma unroll
    for (int p2 = 0; p2 < 4; ++p2)
      pk[p2] = pack_bf2(fmaxf(acc[2 * p2], 0.f), fmaxf(acc[2 * p2 + 1], 0.f));
    *reinterpret_cast<u32x4*>(hws + (size_t)(b0 + b) * 32 + kq * 8) = pk;
  }
}

// ---- main kernel: one (16b x 16r) tile per block ----
// LDS: W_lds bf16 [16b: stride 1168][16r: stride 72][64c] = 37376 B
__global__ __launch_bounds__(256, 4)
void erl_main(const float* __restrict__ v, const float* __restrict__ b2,
              const unsigned short* __restrict__ w2t,
              const unsigned short* __restrict__ hws, float* __restrict__ out) {
  __shared__ __align__(16) unsigned short W_lds[16 * 1168];

  const int t = threadIdx.x;
  const int wid = t >> 6, lane = t & 63;
  const int x = lane >> 4, col = lane & 15;
  const int bid = blockIdx.x;
  const int rt = bid & 7;              // r-tile: XCD-aligned under round-robin
  const int b0 = (bid >> 3) * 16;

  // ---- fragments straight from global (no LDS) ----
  // h^T B-frag: lane holds h[b=col][k=x*8+e]
  bf16x8 hfrag = *reinterpret_cast<const bf16x8*>(&hws[(size_t)(b0 + col) * 32 + x * 8]);
  // M B-frags: lane holds M[b=wid*4+i][c=ch*32+x*8+e][s=min(col,8)]
  const int seff = (col < 9) ? col : 8;
  const int ei = seff / 3;
  const int ej = seff - ei * 3;
  bf16x8 mfr[4][2];
#pragma unroll
  for (int i = 0; i < 4; ++i) {
    int b = wid * 4 + i;
#pragma unroll
    for (int ch = 0; ch < 2; ++ch) {
      const float* vb = v + ((size_t)(b0 + b) * 64 + ch * 32 + x * 8) * 3;
      union { f32x4 q[6]; float f[24]; } u;
#pragma unroll
      for (int l = 0; l < 6; ++l) u.q[l] = reinterpret_cast<const f32x4*>(vb)[l];
      bf16x8 fr;
#pragma unroll
      for (int e = 0; e < 8; ++e) {
        float vx = u.f[e * 3 + 0], vy = u.f[e * 3 + 1], vz = u.f[e * 3 + 2];
        float pa = (ei == 0) ? vx : ((ei == 1) ? vy : vz);
        float pb = (ej == 0) ? vx : ((ej == 1) ? vy : vz);
        fr[e] = (__bf16)(pa * pb);
      }
      mfr[i][ch] = fr;
    }
  }

  // ---- stage 1: w[16b][16r][64c] = W2T @ h^T + b2; wave wid -> tiles tt=0..15 ----
  // rc rows: rt*1024 + wid*256 + tt*16 + (x*4+q); col = b
  const unsigned short* ap = w2t + ((size_t)(rt * 1024 + wid * 256 + col)) * 32 + x * 8;
  const float* b2p = b2 + rt * 1024 + wid * 256 + x * 4;
  const int w_widx = col * 1168 + wid * 288 + x * 4;   // + (tt>>2)*72 + (tt&3)*16

  bf16x8 afA[4], afB[4];
#pragma unroll
  for (int j = 0; j < 4; ++j) afA[j] = *reinterpret_cast<const bf16x8*>(ap + j * 512);
#pragma unroll
  for (int g = 0; g < 4; ++g) {
    if (g < 3) {
#pragma unroll
      for (int j = 0; j < 4; ++j)
        afB[j] = *reinterpret_cast<const bf16x8*>(ap + ((g + 1) * 4 + j) * 512);
    }
#pragma unroll
    for (int j = 0; j < 4; ++j) {
      int tt = g * 4 + j;
      f32x4 acc = *reinterpret_cast<const f32x4*>(b2p + tt * 16);
      acc = __builtin_amdgcn_mfma_f32_16x16x32_bf16(afA[j], hfrag, acc, 0, 0, 0);
      // lane holds w[rc = base + tt*16 + x*4+q][b=col]; r-local = wid*4+(tt>>2), c=(tt&3)*16+x*4+q
      unsigned int* wp = reinterpret_cast<unsigned int*>(&W_lds[w_widx + (tt >> 2) * 72 + (tt & 3) * 16]);
      wp[0] = pack_bf2(acc[0], acc[1]);
      wp[1] = pack_bf2(acc[2], acc[3]);
    }
    if (g < 3) {
      afA[0] = afB[0]; afA[1] = afB[1]; afA[2] = afB[2]; afA[3] = afB[3];
    }
  }
  __syncthreads();

  // ---- stage 2: O[b][16r][9e] = W[r][c] @ M[c][e]; direct global store ----
  const int w_ridx = wid * 4672 + col * 72 + x * 8;    // + i*1168 + ch*32
  const bool do_store = (col < 9);
#pragma unroll
  for (int i = 0; i < 4; ++i) {
    bf16x8 a0 = *reinterpret_cast<const bf16x8*>(&W_lds[w_ridx + i * 1168]);
    bf16x8 a1 = *reinterpret_cast<const bf16x8*>(&W_lds[w_ridx + i * 1168 + 32]);
    f32x4 o = {0.f, 0.f, 0.f, 0.f};
    o = __builtin_amdgcn_mfma_f32_16x16x32_bf16(a0, mfr[i][0], o, 0, 0, 0);
    o = __builtin_amdgcn_mfma_f32_16x16x32_bf16(a1, mfr[i][1], o, 0, 0, 0);
    if (do_store) {
      // D: row r-local = x*4+q, col e = col(<9); r-global = rt*16 + x*4+q
      float* p = out + (size_t)(b0 + wid * 4 + i) * 1152 + rt * 144 + x * 36 + col;
      p[0] = o[0]; p[9] = o[1]; p[18] = o[2]; p[27] = o[3];
    }
  }
}

extern "C" void kernel_launch(void* const* d_in, const int* in_sizes, int n_in,
                              void* d_out, int out_size, void* d_ws, size_t ws_size,
                              hipStream_t stream) {
  const float* v  = (const float*)d_in[0];   // [100000,64,3]
  const float* W1 = (const float*)d_in[1];   // [64,32]
  const float* b1 = (const float*)d_in[2];   // [32]
  const float* W2 = (const float*)d_in[3];   // [32,8192]
  const float* b2 = (const float*)d_in[4];   // [8192]
  float* out = (float*)d_out;                // [100000,128,3,3]

  unsigned short* w2t = (unsigned short*)d_ws;                       // 512 KB
  unsigned short* hws = (unsigned short*)d_ws + 8192 * 32;           // 6.4 MB  [100000][32]

  prep_w2t<<<32, 256, 0, stream>>>(W2, w2t);
  prep_h<<<1563, 256, 0, stream>>>(v, W1, b1, hws);
  erl_main<<<50000, 256, 0, stream>>>(v, b2, w2t, hws, out);
}

// Round 8
// 1010.364 us; speedup vs baseline: 1.3958x; 1.3958x over previous
//
#include <hip/hip_runtime.h>
#include <hip/hip_bf16.h>

// B=100000, C=64, R=128, H=32
// out[b,r,i,j] = sum_c w[b,r,c] * v[b,c,i]*v[b,c,j]
// w = relu(||v||_c @ W1 + b1) @ W2 + b2
//
// R8 = R7 flood structure with write-partition fix:
//   block = (16 batches) x (32 r)  ->  per-b write region = 1152 B = 9 full
//   cache lines, line-aligned, single-writer (no cross-XCD line sharing, no RMW).
//   Two rs sub-phases (16 r each) keep LDS at 37 KB -> 4 blocks/CU.
//   Barriers are lgkmcnt-only + s_barrier (no vmcnt(0) store drain).

typedef float f32x4 __attribute__((ext_vector_type(4)));
typedef __bf16 bf16x8 __attribute__((ext_vector_type(8)));
typedef unsigned int u32x4 __attribute__((ext_vector_type(4)));

static __device__ __forceinline__ unsigned short bf_bits(float f) {
  __hip_bfloat16 h = __float2bfloat16(f);
  return *reinterpret_cast<const unsigned short*>(&h);
}
static __device__ __forceinline__ unsigned int pack_bf2(float a, float b) {
  return (unsigned int)bf_bits(a) | ((unsigned int)bf_bits(b) << 16);
}
static __device__ __forceinline__ void barrier_lds() {
  asm volatile("s_waitcnt lgkmcnt(0)" ::: "memory");
  __builtin_amdgcn_s_barrier();
}

// ---- kernel 0: W2 [32][8192] fp32 -> W2T [8192][32] bf16 ----
__global__ void prep_w2t(const float* __restrict__ W2, unsigned short* __restrict__ w2t) {
  int rc = blockIdx.x * 256 + threadIdx.x;   // 0..8191
  unsigned int u[16];
#pragma unroll
  for (int kp = 0; kp < 16; ++kp) {
    float a = W2[(size_t)(2 * kp) * 8192 + rc];
    float b = W2[(size_t)(2 * kp + 1) * 8192 + rc];
    u[kp] = pack_bf2(a, b);
  }
  unsigned int* dst = reinterpret_cast<unsigned int*>(w2t + (size_t)rc * 32);
#pragma unroll
  for (int j = 0; j < 16; ++j) dst[j] = u[j];
}

// ---- kernel 1: h[b][k] = relu(norm(v[b])@W1 + b1), bf16 [100000][32] ----
__global__ void prep_h(const float* __restrict__ v, const float* __restrict__ W1,
                       const float* __restrict__ b1, unsigned short* __restrict__ hws) {
  __shared__ float v_lds[64 * 192];
  __shared__ float s_lds[64 * 68];
  __shared__ float W1T[32 * 68];
  const int t = threadIdx.x;
  const int b0 = blockIdx.x * 64;
  const int rem = (100000 - b0 < 64) ? (100000 - b0) : 64;

#pragma unroll
  for (int j = 0; j < 8; ++j) {
    int p = t + j * 256;               // W1 [64][32]: c=p>>5, k=p&31
    W1T[(p & 31) * 68 + (p >> 5)] = W1[p];
  }
  {
    const f32x4* src = reinterpret_cast<const f32x4*>(v + (size_t)b0 * 192);
    f32x4* dst = reinterpret_cast<f32x4*>(v_lds);
    const int nq = rem * 48;
#pragma unroll
    for (int j = 0; j < 12; ++j) {
      int p = t + j * 256;
      if (p < nq) dst[p] = src[p];
    }
  }
  __syncthreads();

  const int b = t >> 2, kq = t & 3;
#pragma unroll
  for (int cc = 0; cc < 16; ++cc) {
    int c = kq * 16 + cc;
    float vx = v_lds[b * 192 + c * 3];
    float vy = v_lds[b * 192 + c * 3 + 1];
    float vz = v_lds[b * 192 + c * 3 + 2];
    s_lds[b * 68 + c] = sqrtf(vx * vx + vy * vy + vz * vz);
  }
  __syncthreads();

  if (b < rem) {
    float acc[8];
#pragma unroll
    for (int e = 0; e < 8; ++e) acc[e] = b1[kq * 8 + e];
#pragma unroll
    for (int c4 = 0; c4 < 16; ++c4) {
      f32x4 sv = *reinterpret_cast<const f32x4*>(&s_lds[b * 68 + c4 * 4]);
#pragma unroll
      for (int e = 0; e < 8; ++e) {
        f32x4 wr = *reinterpret_cast<const f32x4*>(&W1T[(kq * 8 + e) * 68 + c4 * 4]);
#pragma unroll
        for (int u = 0; u < 4; ++u) acc[e] = fmaf(sv[u], wr[u], acc[e]);
      }
    }
    u32x4 pk;
#pragma unroll
    for (int p2 = 0; p2 < 4; ++p2)
      pk[p2] = pack_bf2(fmaxf(acc[2 * p2], 0.f), fmaxf(acc[2 * p2 + 1], 0.f));
    *reinterpret_cast<u32x4*>(hws + (size_t)(b0 + b) * 32 + kq * 8) = pk;
  }
}

// ---- main kernel: one (16b x 32r) tile per block, two 16-r sub-phases ----
// LDS: W_lds bf16 [16b: stride 1168][16r: stride 72][64c] = 37376 B
__global__ __launch_bounds__(256, 4)
void erl_main(const float* __restrict__ v, const float* __restrict__ b2,
              const unsigned short* __restrict__ w2t,
              const unsigned short* __restrict__ hws, float* __restrict__ out) {
  __shared__ __align__(16) unsigned short W_lds[16 * 1168];

  const int t = threadIdx.x;
  const int wid = t >> 6, lane = t & 63;
  const int x = lane >> 4, col = lane & 15;
  const int bid = blockIdx.x;
  const int rt2 = bid & 3;             // 32-r tile; XCD-constant under round-robin
  const int b0 = (bid >> 2) * 16;

  // h^T B-frag: lane holds h[b=col][k=x*8+e]
  bf16x8 hfrag = *reinterpret_cast<const bf16x8*>(&hws[(size_t)(b0 + col) * 32 + x * 8]);
  // M B-frags: lane holds M[b=wid*4+i][c=ch*32+x*8+e][s=min(col,8)]
  const int seff = (col < 9) ? col : 8;
  const int ei = seff / 3;
  const int ej = seff - ei * 3;
  bf16x8 mfr[4][2];
#pragma unroll
  for (int i = 0; i < 4; ++i) {
    int b = wid * 4 + i;
#pragma unroll
    for (int ch = 0; ch < 2; ++ch) {
      const float* vb = v + ((size_t)(b0 + b) * 64 + ch * 32 + x * 8) * 3;  // 16B-aligned
      union { f32x4 q[6]; float f[24]; } u;
#pragma unroll
      for (int l = 0; l < 6; ++l) u.q[l] = reinterpret_cast<const f32x4*>(vb)[l];
      bf16x8 fr;
#pragma unroll
      for (int e = 0; e < 8; ++e) {
        float vx = u.f[e * 3 + 0], vy = u.f[e * 3 + 1], vz = u.f[e * 3 + 2];
        float pa = (ei == 0) ? vx : ((ei == 1) ? vy : vz);
        float pb = (ej == 0) ? vx : ((ej == 1) ? vy : vz);
        fr[e] = (__bf16)(pa * pb);
      }
      mfr[i][ch] = fr;
    }
  }

  const int w_widx = col * 1168 + wid * 288 + x * 4;   // + (tt>>2)*72 + (tt&3)*16
  const int w_ridx = wid * 4672 + col * 72 + x * 8;    // + i*1168 + ch*32
  const bool do_store = (col < 9);

#pragma unroll
  for (int rs = 0; rs < 2; ++rs) {
    const int rt = rt2 * 2 + rs;       // 16-r tile index, 0..7
    if (rs) barrier_lds();             // WAR: stage-2 reads done before re-write

    // ---- stage 1: w[16b][16r][64c] = W2T @ h^T + b2; wave wid -> tiles tt=0..15 ----
    const unsigned short* ap = w2t + ((size_t)(rt * 1024 + wid * 256 + col)) * 32 + x * 8;
    const float* b2p = b2 + rt * 1024 + wid * 256 + x * 4;

    bf16x8 afA[4], afB[4];
#pragma unroll
    for (int j = 0; j < 4; ++j) afA[j] = *reinterpret_cast<const bf16x8*>(ap + j * 512);
#pragma unroll
    for (int g = 0; g < 4; ++g) {
      if (g < 3) {
#pragma unroll
        for (int j = 0; j < 4; ++j)
          afB[j] = *reinterpret_cast<const bf16x8*>(ap + ((g + 1) * 4 + j) * 512);
      }
#pragma unroll
      for (int j = 0; j < 4; ++j) {
        int tt = g * 4 + j;
        f32x4 acc = *reinterpret_cast<const f32x4*>(b2p + tt * 16);
        acc = __builtin_amdgcn_mfma_f32_16x16x32_bf16(afA[j], hfrag, acc, 0, 0, 0);
        // lane holds w[rc = tt*16 + x*4+q][b=col]; r-local = wid*4+(tt>>2), c=(tt&3)*16+x*4+q
        unsigned int* wp = reinterpret_cast<unsigned int*>(&W_lds[w_widx + (tt >> 2) * 72 + (tt & 3) * 16]);
        wp[0] = pack_bf2(acc[0], acc[1]);
        wp[1] = pack_bf2(acc[2], acc[3]);
      }
      if (g < 3) {
        afA[0] = afB[0]; afA[1] = afB[1]; afA[2] = afB[2]; afA[3] = afB[3];
      }
    }
    barrier_lds();                     // RAW: stage-1 writes visible

    // ---- stage 2: O[b][16r][9e] = W[r][c] @ M[c][e]; direct global store ----
#pragma unroll
    for (int i = 0; i < 4; ++i) {
      bf16x8 a0 = *reinterpret_cast<const bf16x8*>(&W_lds[w_ridx + i * 1168]);
      bf16x8 a1 = *reinterpret_cast<const bf16x8*>(&W_lds[w_ridx + i * 1168 + 32]);
      f32x4 o = {0.f, 0.f, 0.f, 0.f};
      o = __builtin_amdgcn_mfma_f32_16x16x32_bf16(a0, mfr[i][0], o, 0, 0, 0);
      o = __builtin_amdgcn_mfma_f32_16x16x32_bf16(a1, mfr[i][1], o, 0, 0, 0);
      if (do_store) {
        // D row = x*4+q (r-local), col e = col<9; r-global = rt*16 + x*4+q
        float* p = out + (size_t)(b0 + wid * 4 + i) * 1152 + rt * 144 + x * 36 + col;
        p[0] = o[0]; p[9] = o[1]; p[18] = o[2]; p[27] = o[3];
      }
    }
  }
}

extern "C" void kernel_launch(void* const* d_in, const int* in_sizes, int n_in,
                              void* d_out, int out_size, void* d_ws, size_t ws_size,
                              hipStream_t stream) {
  const float* v  = (const float*)d_in[0];   // [100000,64,3]
  const float* W1 = (const float*)d_in[1];   // [64,32]
  const float* b1 = (const float*)d_in[2];   // [32]
  const float* W2 = (const float*)d_in[3];   // [32,8192]
  const float* b2 = (const float*)d_in[4];   // [8192]
  float* out = (float*)d_out;                // [100000,128,3,3]

  unsigned short* w2t = (unsigned short*)d_ws;                 // 512 KB
  unsigned short* hws = (unsigned short*)d_ws + 8192 * 32;     // 6.4 MB [100000][32]

  prep_w2t<<<32, 256, 0, stream>>>(W2, w2t);
  prep_h<<<1563, 256, 0, stream>>>(v, W1, b1, hws);
  erl_main<<<25000, 256, 0, stream>>>(v, b2, w2t, hws, out);
}

// Round 9
// 816.697 us; speedup vs baseline: 1.7268x; 1.2371x over previous
//
#include <hip/hip_runtime.h>
#include <hip/hip_bf16.h>

// B=100000, C=64, R=128, H=32
// out[b,r,i,j] = sum_c w[b,r,c] * v[b,c,i]*v[b,c,j]
// w = relu(||v||_c @ W1 + b1) @ W2 + b2
//
// R9 = R8 with 256-B false-sharing fix:
//   block = (16 batches) x (64 r) -> per-b write region = 2304 B = 9 x 256 B,
//   256-B-aligned (rt2*2304), single-writer at both 128-B and 256-B granularity.
//   Four rs sub-phases (16 r each); LDS / stores / phases byte-identical to R8.
//   rt2 = bid&1 stays XCD-constant under round-robin -> 256 KB w2t slice per XCD L2.

typedef float f32x4 __attribute__((ext_vector_type(4)));
typedef __bf16 bf16x8 __attribute__((ext_vector_type(8)));
typedef unsigned int u32x4 __attribute__((ext_vector_type(4)));

static __device__ __forceinline__ unsigned short bf_bits(float f) {
  __hip_bfloat16 h = __float2bfloat16(f);
  return *reinterpret_cast<const unsigned short*>(&h);
}
static __device__ __forceinline__ unsigned int pack_bf2(float a, float b) {
  return (unsigned int)bf_bits(a) | ((unsigned int)bf_bits(b) << 16);
}
static __device__ __forceinline__ void barrier_lds() {
  asm volatile("s_waitcnt lgkmcnt(0)" ::: "memory");
  __builtin_amdgcn_s_barrier();
}

// ---- kernel 0: W2 [32][8192] fp32 -> W2T [8192][32] bf16 ----
__global__ void prep_w2t(const float* __restrict__ W2, unsigned short* __restrict__ w2t) {
  int rc = blockIdx.x * 256 + threadIdx.x;   // 0..8191
  unsigned int u[16];
#pragma unroll
  for (int kp = 0; kp < 16; ++kp) {
    float a = W2[(size_t)(2 * kp) * 8192 + rc];
    float b = W2[(size_t)(2 * kp + 1) * 8192 + rc];
    u[kp] = pack_bf2(a, b);
  }
  unsigned int* dst = reinterpret_cast<unsigned int*>(w2t + (size_t)rc * 32);
#pragma unroll
  for (int j = 0; j < 16; ++j) dst[j] = u[j];
}

// ---- kernel 1: h[b][k] = relu(norm(v[b])@W1 + b1), bf16 [100000][32] ----
__global__ void prep_h(const float* __restrict__ v, const float* __restrict__ W1,
                       const float* __restrict__ b1, unsigned short* __restrict__ hws) {
  __shared__ float v_lds[64 * 192];
  __shared__ float s_lds[64 * 68];
  __shared__ float W1T[32 * 68];
  const int t = threadIdx.x;
  const int b0 = blockIdx.x * 64;
  const int rem = (100000 - b0 < 64) ? (100000 - b0) : 64;

#pragma unroll
  for (int j = 0; j < 8; ++j) {
    int p = t + j * 256;               // W1 [64][32]: c=p>>5, k=p&31
    W1T[(p & 31) * 68 + (p >> 5)] = W1[p];
  }
  {
    const f32x4* src = reinterpret_cast<const f32x4*>(v + (size_t)b0 * 192);
    f32x4* dst = reinterpret_cast<f32x4*>(v_lds);
    const int nq = rem * 48;
#pragma unroll
    for (int j = 0; j < 12; ++j) {
      int p = t + j * 256;
      if (p < nq) dst[p] = src[p];
    }
  }
  __syncthreads();

  const int b = t >> 2, kq = t & 3;
#pragma unroll
  for (int cc = 0; cc < 16; ++cc) {
    int c = kq * 16 + cc;
    float vx = v_lds[b * 192 + c * 3];
    float vy = v_lds[b * 192 + c * 3 + 1];
    float vz = v_lds[b * 192 + c * 3 + 2];
    s_lds[b * 68 + c] = sqrtf(vx * vx + vy * vy + vz * vz);
  }
  __syncthreads();

  if (b < rem) {
    float acc[8];
#pragma unroll
    for (int e = 0; e < 8; ++e) acc[e] = b1[kq * 8 + e];
#pragma unroll
    for (int c4 = 0; c4 < 16; ++c4) {
      f32x4 sv = *reinterpret_cast<const f32x4*>(&s_lds[b * 68 + c4 * 4]);
#pragma unroll
      for (int e = 0; e < 8; ++e) {
        f32x4 wr = *reinterpret_cast<const f32x4*>(&W1T[(kq * 8 + e) * 68 + c4 * 4]);
#pragma unroll
        for (int u = 0; u < 4; ++u) acc[e] = fmaf(sv[u], wr[u], acc[e]);
      }
    }
    u32x4 pk;
#pragma unroll
    for (int p2 = 0; p2 < 4; ++p2)
      pk[p2] = pack_bf2(fmaxf(acc[2 * p2], 0.f), fmaxf(acc[2 * p2 + 1], 0.f));
    *reinterpret_cast<u32x4*>(hws + (size_t)(b0 + b) * 32 + kq * 8) = pk;
  }
}

// ---- main kernel: one (16b x 64r) tile per block, four 16-r sub-phases ----
// LDS: W_lds bf16 [16b: stride 1168][16r: stride 72][64c] = 37376 B
__global__ __launch_bounds__(256, 4)
void erl_main(const float* __restrict__ v, const float* __restrict__ b2,
              const unsigned short* __restrict__ w2t,
              const unsigned short* __restrict__ hws, float* __restrict__ out) {
  __shared__ __align__(16) unsigned short W_lds[16 * 1168];

  const int t = threadIdx.x;
  const int wid = t >> 6, lane = t & 63;
  const int x = lane >> 4, col = lane & 15;
  const int bid = blockIdx.x;
  const int rt2 = bid & 1;             // 64-r tile; XCD-constant under round-robin
  const int b0 = (bid >> 1) * 16;

  // h^T B-frag: lane holds h[b=col][k=x*8+e]
  bf16x8 hfrag = *reinterpret_cast<const bf16x8*>(&hws[(size_t)(b0 + col) * 32 + x * 8]);
  // M B-frags: lane holds M[b=wid*4+i][c=ch*32+x*8+e][s=min(col,8)]
  const int seff = (col < 9) ? col : 8;
  const int ei = seff / 3;
  const int ej = seff - ei * 3;
  bf16x8 mfr[4][2];
#pragma unroll
  for (int i = 0; i < 4; ++i) {
    int b = wid * 4 + i;
#pragma unroll
    for (int ch = 0; ch < 2; ++ch) {
      const float* vb = v + ((size_t)(b0 + b) * 64 + ch * 32 + x * 8) * 3;  // 16B-aligned
      union { f32x4 q[6]; float f[24]; } u;
#pragma unroll
      for (int l = 0; l < 6; ++l) u.q[l] = reinterpret_cast<const f32x4*>(vb)[l];
      bf16x8 fr;
#pragma unroll
      for (int e = 0; e < 8; ++e) {
        float vx = u.f[e * 3 + 0], vy = u.f[e * 3 + 1], vz = u.f[e * 3 + 2];
        float pa = (ei == 0) ? vx : ((ei == 1) ? vy : vz);
        float pb = (ej == 0) ? vx : ((ej == 1) ? vy : vz);
        fr[e] = (__bf16)(pa * pb);
      }
      mfr[i][ch] = fr;
    }
  }

  const int w_widx = col * 1168 + wid * 288 + x * 4;   // + (tt>>2)*72 + (tt&3)*16
  const int w_ridx = wid * 4672 + col * 72 + x * 8;    // + i*1168 + ch*32
  const bool do_store = (col < 9);

#pragma unroll
  for (int rs = 0; rs < 4; ++rs) {
    const int rt = rt2 * 4 + rs;       // 16-r tile index, 0..7
    if (rs) barrier_lds();             // WAR: stage-2 reads done before re-write

    // ---- stage 1: w[16b][16r][64c] = W2T @ h^T + b2; wave wid -> tiles tt=0..15 ----
    const unsigned short* ap = w2t + ((size_t)(rt * 1024 + wid * 256 + col)) * 32 + x * 8;
    const float* b2p = b2 + rt * 1024 + wid * 256 + x * 4;

    bf16x8 afA[4], afB[4];
#pragma unroll
    for (int j = 0; j < 4; ++j) afA[j] = *reinterpret_cast<const bf16x8*>(ap + j * 512);
#pragma unroll
    for (int g = 0; g < 4; ++g) {
      if (g < 3) {
#pragma unroll
        for (int j = 0; j < 4; ++j)
          afB[j] = *reinterpret_cast<const bf16x8*>(ap + ((g + 1) * 4 + j) * 512);
      }
#pragma unroll
      for (int j = 0; j < 4; ++j) {
        int tt = g * 4 + j;
        f32x4 acc = *reinterpret_cast<const f32x4*>(b2p + tt * 16);
        acc = __builtin_amdgcn_mfma_f32_16x16x32_bf16(afA[j], hfrag, acc, 0, 0, 0);
        // lane holds w[rc = tt*16 + x*4+q][b=col]; r-local = wid*4+(tt>>2), c=(tt&3)*16+x*4+q
        unsigned int* wp = reinterpret_cast<unsigned int*>(&W_lds[w_widx + (tt >> 2) * 72 + (tt & 3) * 16]);
        wp[0] = pack_bf2(acc[0], acc[1]);
        wp[1] = pack_bf2(acc[2], acc[3]);
      }
      if (g < 3) {
        afA[0] = afB[0]; afA[1] = afB[1]; afA[2] = afB[2]; afA[3] = afB[3];
      }
    }
    barrier_lds();                     // RAW: stage-1 writes visible

    // ---- stage 2: O[b][16r][9e] = W[r][c] @ M[c][e]; direct global store ----
#pragma unroll
    for (int i = 0; i < 4; ++i) {
      bf16x8 a0 = *reinterpret_cast<const bf16x8*>(&W_lds[w_ridx + i * 1168]);
      bf16x8 a1 = *reinterpret_cast<const bf16x8*>(&W_lds[w_ridx + i * 1168 + 32]);
      f32x4 o = {0.f, 0.f, 0.f, 0.f};
      o = __builtin_amdgcn_mfma_f32_16x16x32_bf16(a0, mfr[i][0], o, 0, 0, 0);
      o = __builtin_amdgcn_mfma_f32_16x16x32_bf16(a1, mfr[i][1], o, 0, 0, 0);
      if (do_store) {
        // D row = x*4+q (r-local), col e = col<9; r-global = rt*16 + x*4+q
        float* p = out + (size_t)(b0 + wid * 4 + i) * 1152 + rt * 144 + x * 36 + col;
        p[0] = o[0]; p[9] = o[1]; p[18] = o[2]; p[27] = o[3];
      }
    }
  }
}

extern "C" void kernel_launch(void* const* d_in, const int* in_sizes, int n_in,
                              void* d_out, int out_size, void* d_ws, size_t ws_size,
                              hipStream_t stream) {
  const float* v  = (const float*)d_in[0];   // [100000,64,3]
  const float* W1 = (const float*)d_in[1];   // [64,32]
  const float* b1 = (const float*)d_in[2];   // [32]
  const float* W2 = (const float*)d_in[3];   // [32,8192]
  const float* b2 = (const float*)d_in[4];   // [8192]
  float* out = (float*)d_out;                // [100000,128,3,3]

  unsigned short* w2t = (unsigned short*)d_ws;                 // 512 KB
  unsigned short* hws = (unsigned short*)d_ws + 8192 * 32;     // 6.4 MB [100000][32]

  prep_w2t<<<32, 256, 0, stream>>>(W2, w2t);
  prep_h<<<1563, 256, 0, stream>>>(v, W1, b1, hws);
  erl_main<<<12500, 256, 0, stream>>>(v, b2, w2t, hws, out);
}